// Round 3
// baseline (609.905 us; speedup 1.0000x reference)
//
#include <hip/hip_runtime.h>

#define NZ 81          // 9x9 zones
#define OBS_DIM 48
#define MAX_ADJ 5
#define NEG_INF -1000000000.0f
#define BLOCK 512
#define NTASK (NZ * MAX_ADJ)   // 405 (n,k) tasks

__global__ __launch_bounds__(BLOCK) void taxi_actor_kernel(
    const float* __restrict__ obs,   // [B, 48]
    const float* __restrict__ W,     // [81, 48, 5]
    const float* __restrict__ bias,  // [81, 5]
    const int*   __restrict__ idx,   // [81, 5]
    const float* __restrict__ mask,  // [81, 5]
    float* __restrict__ out)         // [B, 81, 81]
{
    __shared__ float s_obs[OBS_DIM];
    __shared__ float s_logits[NTASK];     // [n][k] masked logits
    __shared__ float s_out[NZ * NZ];      // 26244 B output tile

    const int b   = blockIdx.x;
    const int tid = threadIdx.x;

    // Load obs row; zero the output tile.
    if (tid < OBS_DIM) s_obs[tid] = obs[(size_t)b * OBS_DIM + tid];
    for (int i = tid; i < NZ * NZ; i += BLOCK) s_out[i] = 0.0f;
    __syncthreads();

    // Phase 1: one thread per (n,k). Adjacent lanes -> adjacent W addresses
    // (5-float segments), so wave loads coalesce instead of 64-line gathers.
    if (tid < NTASK) {
        const int n = tid / MAX_ADJ;
        const int k = tid - n * MAX_ADJ;
        const float* __restrict__ Wp = W + (size_t)n * OBS_DIM * MAX_ADJ + k;
        float acc = bias[tid];
        #pragma unroll
        for (int d = 0; d < OBS_DIM; ++d)
            acc = fmaf(s_obs[d], Wp[d * MAX_ADJ], acc);
        s_logits[tid] = (mask[tid] > 0.0f) ? acc : NEG_INF;
    }
    __syncthreads();

    // Phase 2: 81 threads, 5-way masked softmax + scatter into the tile.
    if (tid < NZ) {
        float l[MAX_ADJ];
        float m = NEG_INF;
        #pragma unroll
        for (int k = 0; k < MAX_ADJ; ++k) {
            l[k] = s_logits[tid * MAX_ADJ + k];
            m = fmaxf(m, l[k]);
        }
        float p[MAX_ADJ];
        float s = 0.0f;
        #pragma unroll
        for (int k = 0; k < MAX_ADJ; ++k) {
            p[k] = __expf(l[k] - m);   // masked -> exp(-1e9-m) underflows to 0
            s += p[k];
        }
        const float inv = 1.0f / s;
        #pragma unroll
        for (int k = 0; k < MAX_ADJ; ++k) {
            if (mask[tid * MAX_ADJ + k] > 0.0f) {
                const int z = idx[tid * MAX_ADJ + k];  // distinct per k within n
                s_out[tid * NZ + z] = p[k] * inv;
            }
        }
    }
    __syncthreads();

    // Phase 3: coalesced streaming store of the 81x81 tile.
    float* __restrict__ outb = out + (size_t)b * (NZ * NZ);
    for (int i = tid; i < NZ * NZ; i += BLOCK) outb[i] = s_out[i];
}

extern "C" void kernel_launch(void* const* d_in, const int* in_sizes, int n_in,
                              void* d_out, int out_size, void* d_ws, size_t ws_size,
                              hipStream_t stream) {
    const float* obs  = (const float*)d_in[0];
    const float* W    = (const float*)d_in[1];
    const float* bias = (const float*)d_in[2];
    const int*   idx  = (const int*)d_in[3];
    const float* mask = (const float*)d_in[4];
    float* out = (float*)d_out;

    const int B = in_sizes[0] / OBS_DIM;   // 32768

    taxi_actor_kernel<<<B, BLOCK, 0, stream>>>(obs, W, bias, idx, mask, out);
}

// Round 4
// 177.076 us; speedup vs baseline: 3.4443x; 3.4443x over previous
//
#include <hip/hip_runtime.h>

#define NZ 81          // 9x9 zones
#define OBS_DIM 48
#define MAX_ADJ 5
#define NTASK (NZ * MAX_ADJ)   // 405
#define NEG_INF -1000000000.0f
#define BLOCK 512
#define ROWS 16        // batch rows per block; W regs amortized across these

__global__ __launch_bounds__(BLOCK) void taxi_actor_kernel(
    const float* __restrict__ obs,   // [B, 48]
    const float* __restrict__ W,     // [81, 48, 5]
    const float* __restrict__ bias,  // [81, 5]
    const int*   __restrict__ idx,   // [81, 5]
    const float* __restrict__ mask,  // [81, 5]
    float* __restrict__ out)         // [B, 81, 81]
{
    __shared__ float s_obs[ROWS * OBS_DIM];   // 3 KB
    __shared__ float s_logits[NTASK];         // 1.6 KB
    __shared__ int   s_idx[NTASK];            // 1.6 KB (masked -> -1)
    __shared__ float s_tile[NZ * NZ];         // 26.2 KB

    const int tid = threadIdx.x;
    const size_t b0 = (size_t)blockIdx.x * ROWS;

    // Coalesced stage of 16 obs rows.
    for (int i = tid; i < ROWS * OBS_DIM; i += BLOCK)
        s_obs[i] = obs[b0 * OBS_DIM + i];
    // Zero tile ONCE: scatter positions are identical for every row, so
    // non-scattered entries remain 0 and scattered ones are overwritten.
    for (int i = tid; i < NZ * NZ; i += BLOCK)
        s_tile[i] = 0.0f;

    // Per-task constants + W column in registers (read once, reused 16 rows).
    float w[OBS_DIM];
    float bia = 0.0f;
    if (tid < NTASK) {
        const int n = tid / MAX_ADJ;
        const int k = tid - n * MAX_ADJ;
        const float* __restrict__ Wp = W + (size_t)n * (OBS_DIM * MAX_ADJ) + k;
        #pragma unroll
        for (int d = 0; d < OBS_DIM; ++d) w[d] = Wp[d * MAX_ADJ];
        bia = bias[tid];
        s_idx[tid] = (mask[tid] > 0.0f) ? idx[tid] : -1;
    }
    __syncthreads();

    for (int r = 0; r < ROWS; ++r) {
        // Dot in registers; obs is an LDS broadcast (all lanes same address).
        float acc = bia;
        if (tid < NTASK) {
            const float* __restrict__ o = s_obs + r * OBS_DIM;
            #pragma unroll
            for (int d = 0; d < OBS_DIM; ++d)
                acc = fmaf(o[d], w[d], acc);
        }
        __syncthreads();   // (1) prev row's store done reading s_tile/s_logits
        if (tid < NTASK)
            s_logits[tid] = (s_idx[tid] >= 0) ? acc : NEG_INF;
        __syncthreads();   // (2) logits visible
        if (tid < NZ) {
            float l[MAX_ADJ], p[MAX_ADJ];
            float m = NEG_INF;
            #pragma unroll
            for (int k = 0; k < MAX_ADJ; ++k) {
                l[k] = s_logits[tid * MAX_ADJ + k];
                m = fmaxf(m, l[k]);
            }
            float s = 0.0f;
            #pragma unroll
            for (int k = 0; k < MAX_ADJ; ++k) {
                p[k] = __expf(l[k] - m);   // masked: exp(-1e9) -> 0
                s += p[k];
            }
            const float inv = 1.0f / s;
            #pragma unroll
            for (int k = 0; k < MAX_ADJ; ++k) {
                const int z = s_idx[tid * MAX_ADJ + k];
                if (z >= 0) s_tile[tid * NZ + z] = p[k] * inv;
            }
        }
        __syncthreads();   // (3) tile ready
        // Coalesced streaming store of the 81x81 tile.
        float* __restrict__ outb = out + (b0 + r) * (size_t)(NZ * NZ);
        for (int i = tid; i < NZ * NZ; i += BLOCK)
            outb[i] = s_tile[i];
    }
}

extern "C" void kernel_launch(void* const* d_in, const int* in_sizes, int n_in,
                              void* d_out, int out_size, void* d_ws, size_t ws_size,
                              hipStream_t stream) {
    const float* obs  = (const float*)d_in[0];
    const float* W    = (const float*)d_in[1];
    const float* bias = (const float*)d_in[2];
    const int*   idx  = (const int*)d_in[3];
    const float* mask = (const float*)d_in[4];
    float* out = (float*)d_out;

    const int B = in_sizes[0] / OBS_DIM;   // 32768, divisible by ROWS
    taxi_actor_kernel<<<B / ROWS, BLOCK, 0, stream>>>(obs, W, bias, idx, mask, out);
}